// Round 4
// baseline (192.454 us; speedup 1.0000x reference)
//
#include <hip/hip_runtime.h>
#include <math.h>

// DiffKS round 7.
// Fit of r3/r5/r6 counters: per-body cost ≈ 70 cy + ~31 cy per ON-CHAIN DS
// instruction (history reads/writes feeding the next FMA chain via lgkmcnt);
// off-chain DS ≈ 5 cy; VMEM irrelevant (r6 proved). So this round minimizes
// on-chain DS ops: 18 -> 6 per body.
//   * Kernel A pre-shifts the 7 negated taps into an 8-slot zero-padded
//     array keyed by off = q&1 and stores the 8B-aligned window base
//     base2 = (q&~1)&1023. 12 floats/sample in ws.
//   * Kernel B reads each sample's history window as 4x float2 from base2
//     (merges to ds_read2_b64) instead of 7x b32 — FMA term order is
//     bit-identical (extra tap multiplies by +-0).
//   * Coefs staged per 8-body group into LDS via global_load_lds (proven
//     off-chain in r6), read 3x b128 per sample one body ahead.
//   * Mirror writes: rare wave-uniform branch instead of per-body dumps.

#define T_SAMPLES 44100
#define NFRAMES   100
#define NCOEF     6
#define NACT      7
#define BURST     2048
#define EXC_ORD   5

#define C2        100           // samples per body
#define HISTSZ    1096          // 1024 ring + 6 mirror + pad + 64 dump slots
#define GRPF      9600          // 800 samples * 12 floats per group

#define WS_COEF_FLOATS (T_SAMPLES * 12)
#define WS_EXC_OFF     WS_COEF_FLOATS
#define WS_EXC_FLOATS  (EXC_ORD * BURST)
#define WS_TOTAL_BYTES ((size_t)(WS_COEF_FLOATS + WS_EXC_FLOATS) * 4)

// ---------------------------------------------------------------- kernel A
__global__ __launch_bounds__(256) void diffks_precompute(
    const float* __restrict__ delay_frames,
    const float* __restrict__ raw_coeff,
    const float* __restrict__ raw_gain,
    const float* __restrict__ exc_coeff,
    float* __restrict__ ws)
{
    int g = blockIdx.x * 256 + threadIdx.x;
    const float gain = 0.1f / (1.0f + expf(-raw_gain[0])) + 0.9f;

    if (g < T_SAMPLES) {
        const float stepT = 99.0f / (float)(T_SAMPLES - 1);
        float pos = (float)g * stepT;
        int i0 = (int)pos; if (i0 > NFRAMES - 2) i0 = NFRAMES - 2;
        float w = pos - (float)i0;

        float d0 = delay_frames[i0], d1 = delay_frames[i0 + 1];
        float delay = d0 + (d1 - d0) * w;
        int z = (int)delay;                  // delay >= 100 > 0
        float alfa = delay - (float)z;

        float b[NCOEF];
        {
            float c0v[NCOEF], c1v[NCOEF];
            float s0 = 0.f, s1 = 0.f;
            #pragma unroll
            for (int j = 0; j < NCOEF; ++j) {
                c0v[j] = 1.0f / (1.0f + expf(-raw_coeff[i0 * NCOEF + j]));
                c1v[j] = 1.0f / (1.0f + expf(-raw_coeff[(i0 + 1) * NCOEF + j]));
                s0 += c0v[j]; s1 += c1v[j];
            }
            float g0 = gain / s0, g1 = gain / s1;
            #pragma unroll
            for (int j = 0; j < NCOEF; ++j) {
                float x0 = c0v[j] * g0, x1 = c1v[j] * g1;
                b[j] = x0 + (x1 - x0) * w;
            }
        }
        // v_j exactly as previous rounds (bit-identical), then negate (exact)
        float oma = 1.0f - alfa;
        float v0 = -oma * b[0];
        float v1 = -(alfa * b[0] + oma * b[1]);
        float v2 = -(alfa * b[1] + oma * b[2]);
        float v3 = -(alfa * b[2] + oma * b[3]);
        float v4 = -(alfa * b[3] + oma * b[4]);
        float v5 = -(alfa * b[4] + oma * b[5]);
        float v6 = -alfa * b[5];
        float pv0 = -v0, pv1 = -v1, pv2 = -v2, pv3 = -v3;
        float pv4 = -v4, pv5 = -v5, pv6 = -v6;

        int base = g - z - 1;
        int q = base - 6;                    // window = y[q .. q+6]
        int off = q & 1;
        unsigned b2 = ((unsigned)q) & 1022u; // (q & ~1) & 1023, 8B-aligned

        // shifted taps: m[off+6-j] = pv_j  (FMA iterates i = 7..0)
        float m0, m1, m2, m3, m4, m5, m6, m7;
        if (off) { m0 = 0.f; m1 = pv6; m2 = pv5; m3 = pv4;
                   m4 = pv3; m5 = pv2; m6 = pv1; m7 = pv0; }
        else     { m0 = pv6; m1 = pv5; m2 = pv4; m3 = pv3;
                   m4 = pv2; m5 = pv1; m6 = pv0; m7 = 0.f; }

        float4* o = (float4*)(ws + (size_t)g * 12);
        o[0] = make_float4(m0, m1, m2, m3);
        o[1] = make_float4(m4, m5, m6, m7);
        o[2] = make_float4(__int_as_float((int)b2), 0.f, 0.f, 0.f);
    } else if (g < T_SAMPLES + BURST) {
        int te = g - T_SAMPLES;
        const float stepE = 99.0f / (float)(BURST - 1);
        float pos = (float)te * stepE;
        int i0 = (int)pos; if (i0 > NFRAMES - 2) i0 = NFRAMES - 2;
        float w = pos - (float)i0;
        float* o = ws + WS_EXC_OFF + te * EXC_ORD;     // interleaved [t*5+k]
        #pragma unroll
        for (int k = 0; k < EXC_ORD; ++k) {
            float a0 = exc_coeff[i0 * EXC_ORD + k];
            float a1 = exc_coeff[(i0 + 1) * EXC_ORD + k];
            o[k] = a0 + (a1 - a0) * w;
        }
    }
}

// async global->LDS copy, 16B per lane; LDS base must be wave-uniform
__device__ __forceinline__ void gload_lds16(const float* g, float* l) {
    __builtin_amdgcn_global_load_lds(
        (const __attribute__((address_space(1))) unsigned int*)(g),
        (__attribute__((address_space(3))) unsigned int*)(l),
        16, 0, 0);
}

// ---------------------------------------------------------------- kernel B
__global__ __launch_bounds__(64, 1) void diffks_serial(
    const float* __restrict__ excitation,
    const float* __restrict__ ws,
    float* __restrict__ out)
{
    __shared__ float s_cf[2][GRPF];      // coefficient double buffer (t-order)
    __shared__ float s_x[64][33];        // burst (padded rows)
    __shared__ float s_a[64][161];       // exc coefs [seg][(i%32)*5+k]
    __shared__ float s_hist[HISTSZ];     // 1024 ring + 6 mirror + 64 dump
    __shared__ float s_tail[64][32];
    __shared__ float s_bound[64][6];

    const int lane = threadIdx.x;

    // ---- stage ----
    for (int t = lane; t < BURST; t += 64)
        s_x[t >> 5][t & 31] = excitation[t];
    {   // exc coefs: lane handles t = lane + 64*i, 5 contiguous scalars each
        for (int i = 0; i < 32; ++i) {
            int t = lane + i * 64;
            const float* g = ws + WS_EXC_OFF + t * EXC_ORD;
            float* dst = &s_a[t >> 5][(t & 31) * 5];
            dst[0] = g[0]; dst[1] = g[1]; dst[2] = g[2];
            dst[3] = g[3]; dst[4] = g[4];
        }
    }
    for (int i = lane; i < HISTSZ; i += 64) s_hist[i] = 0.0f;
    __syncthreads();

    // ---- phase 1: excitation LPC via 64-segment state-space scan ----
    {
        float st[6][5];
        #pragma unroll
        for (int r = 0; r < 6; ++r)
            #pragma unroll
            for (int k = 0; k < 5; ++k) st[r][k] = 0.0f;
        #pragma unroll
        for (int r = 1; r <= 5; ++r) st[r][r - 1] = 1.0f;

        const float* ar = &s_a[lane][0];
        const float* xr = &s_x[lane][0];
        #pragma unroll 8
        for (int i = 0; i < 32; ++i) {
            float a0 = ar[i * 5 + 0], a1 = ar[i * 5 + 1], a2 = ar[i * 5 + 2];
            float a3 = ar[i * 5 + 3], a4 = ar[i * 5 + 4];
            float xv = xr[i];
            #pragma unroll
            for (int r = 0; r < 6; ++r) {
                float acc = (r == 0) ? xv : 0.0f;
                acc = fmaf(-a0, st[r][0], acc);
                acc = fmaf(-a1, st[r][1], acc);
                acc = fmaf(-a2, st[r][2], acc);
                acc = fmaf(-a3, st[r][3], acc);
                acc = fmaf(-a4, st[r][4], acc);
                st[r][4] = st[r][3]; st[r][3] = st[r][2];
                st[r][2] = st[r][1]; st[r][1] = st[r][0];
                st[r][0] = acc;
            }
        }
        #pragma unroll
        for (int r = 0; r < 6; ++r)
            #pragma unroll
            for (int k = 0; k < 5; ++k)
                s_tail[lane][r * 5 + k] = st[r][k];
    }
    __syncthreads();

    if (lane == 0) {   // chain 5-dim boundary states through 64 segments
        float Y[5] = {0.f, 0.f, 0.f, 0.f, 0.f};
        for (int l = 0; l < 64; ++l) {
            #pragma unroll
            for (int c = 0; c < 5; ++c) s_bound[l][c] = Y[c];
            float tl[30];
            #pragma unroll
            for (int j = 0; j < 30; ++j) tl[j] = s_tail[l][j];
            float ny[5];
            #pragma unroll
            for (int k = 0; k < 5; ++k) {
                float acc = tl[k];
                #pragma unroll
                for (int c = 1; c <= 5; ++c)
                    acc = fmaf(tl[c * 5 + k], Y[c - 1], acc);
                ny[k] = acc;
            }
            #pragma unroll
            for (int k = 0; k < 5; ++k) Y[k] = ny[k];
        }
    }
    __syncthreads();

    {   // re-run each segment with correct boundary state
        float b0 = s_bound[lane][0], b1 = s_bound[lane][1], b2 = s_bound[lane][2];
        float b3 = s_bound[lane][3], b4 = s_bound[lane][4];
        const float* ar = &s_a[lane][0];
        float* xr = &s_x[lane][0];
        #pragma unroll 8
        for (int i = 0; i < 32; ++i) {
            float a0 = ar[i * 5 + 0], a1 = ar[i * 5 + 1], a2 = ar[i * 5 + 2];
            float a3 = ar[i * 5 + 3], a4 = ar[i * 5 + 4];
            float acc = xr[i];
            acc = fmaf(-a0, b0, acc);
            acc = fmaf(-a1, b1, acc);
            acc = fmaf(-a2, b2, acc);
            acc = fmaf(-a3, b3, acc);
            acc = fmaf(-a4, b4, acc);
            b4 = b3; b3 = b2; b2 = b1; b1 = b0; b0 = acc;
            xr[i] = acc;
        }
    }
    __syncthreads();

    // ---- phase 2: barrier-free resonator, C=100, 2 samples/lane ----
    const bool lane_act = (lane < 50);
    const unsigned dumpA = 1032u + (unsigned)lane;   // per-lane dump slot

    #define STAGE_GRP(gg)                                                      \
    {                                                                          \
        float* dstb = s_cf[(gg) & 1];                                          \
        const float* srcb = ws + (size_t)(gg) * GRPF + lane * 4;               \
        const int nis = ((gg) == 55) ? 5 : 38;                                 \
        for (int i = 0; i < nis; ++i)                                          \
            gload_lds16(srcb + i * 256, dstb + i * 256);                       \
    }

    // prologue: stage group 0, wait, load body-0 coefs into ring slot 0
    STAGE_GRP(0)
    asm volatile("s_waitcnt vmcnt(0)" ::: "memory");

    // coef ring: depth 2, slot = body&1. [sample][reg]: reg0=m0..3,
    // reg1=m4..7, reg2.x=base2 (int bits).
    float4 CF[2][2][3];
    {
        const float4* qA = (const float4*)(s_cf[0] + lane * 12);
        const float4* qB = (const float4*)(s_cf[0] + (lane + 50) * 12);
        CF[0][0][0] = qA[0]; CF[0][0][1] = qA[1]; CF[0][0][2] = qA[2];
        CF[0][1][0] = qB[0]; CF[0][1][1] = qB[1]; CF[0][1][2] = qB[2];
    }

    // hw[parity][sample][k]: 8-float aligned history window; body 0 reads
    // only pre-start zeros (base < 0 for every lane since z >= 100).
    float hw[2][2][8];
    #pragma unroll
    for (int k = 0; k < 8; ++k) {
        hw[0][0][k] = 0.f; hw[0][1][k] = 0.f;
        hw[1][0][k] = 0.f; hw[1][1][k] = 0.f;
    }

    // Body j of current group (cc = g*8 + j):
    //  1. coef LDS reads (3x b128 per sample) for body cc+1 -> slot (j+1)&1
    //  2. 16 FMAs (two independent 8-chains), exact original term order
    //  3. 2 ring ds_writes (+ rare wave-uniform mirror branch)
    //  4. window reads for body cc+1: 4x float2 per sample from base2
    #define KS4_BODY(j, WITHX, DO_NEXT)                                        \
    {                                                                          \
        if (DO_NEXT) {                                                         \
            const float* cbuf = ((j) < 7) ? cfc : cfn;                         \
            const int ln = (((j) + 1) & 7) * 100 + lane;                       \
            const float4* qA = (const float4*)(cbuf + ln * 12);                \
            const float4* qB = (const float4*)(cbuf + (ln + 50) * 12);         \
            CF[((j) + 1) & 1][0][0] = qA[0];                                   \
            CF[((j) + 1) & 1][0][1] = qA[1];                                   \
            CF[((j) + 1) & 1][0][2] = qA[2];                                   \
            CF[((j) + 1) & 1][1][0] = qB[0];                                   \
            CF[((j) + 1) & 1][1][1] = qB[1];                                   \
            CF[((j) + 1) & 1][1][2] = qB[2];                                   \
        }                                                                      \
        const float4 am0 = CF[(j) & 1][0][0], am1 = CF[(j) & 1][0][1];         \
        const float4 bm0 = CF[(j) & 1][1][0], bm1 = CF[(j) & 1][1][1];         \
        const int tA = cb100 + (j) * 100 + lane;                               \
        const int tB = tA + 50;                                                \
        float accA, accB;                                                      \
        if (WITHX) {                                                           \
            accA = (lane_act && tA < BURST) ? s_x[tA >> 5][tA & 31] : 0.0f;    \
            accB = (lane_act && tB < BURST) ? s_x[tB >> 5][tB & 31] : 0.0f;    \
        } else { accA = 0.0f; accB = 0.0f; }                                   \
        accA = fmaf(am1.w, hw[(j) & 1][0][7], accA);                           \
        accB = fmaf(bm1.w, hw[(j) & 1][1][7], accB);                           \
        accA = fmaf(am1.z, hw[(j) & 1][0][6], accA);                           \
        accB = fmaf(bm1.z, hw[(j) & 1][1][6], accB);                           \
        accA = fmaf(am1.y, hw[(j) & 1][0][5], accA);                           \
        accB = fmaf(bm1.y, hw[(j) & 1][1][5], accB);                           \
        accA = fmaf(am1.x, hw[(j) & 1][0][4], accA);                           \
        accB = fmaf(bm1.x, hw[(j) & 1][1][4], accB);                           \
        accA = fmaf(am0.w, hw[(j) & 1][0][3], accA);                           \
        accB = fmaf(bm0.w, hw[(j) & 1][1][3], accB);                           \
        accA = fmaf(am0.z, hw[(j) & 1][0][2], accA);                           \
        accB = fmaf(bm0.z, hw[(j) & 1][1][2], accB);                           \
        accA = fmaf(am0.y, hw[(j) & 1][0][1], accA);                           \
        accB = fmaf(bm0.y, hw[(j) & 1][1][1], accB);                           \
        accA = fmaf(am0.x, hw[(j) & 1][0][0], accA);                           \
        accB = fmaf(bm0.x, hw[(j) & 1][1][0], accB);                           \
        const unsigned pA_ = ((unsigned)tA) & 1023u;                           \
        const unsigned pB_ = ((unsigned)tB) & 1023u;                           \
        s_hist[lane_act ? pA_ : dumpA] = accA;                                 \
        s_hist[lane_act ? pB_ : dumpA] = accB;                                 \
        {                                                                      \
            const unsigned pm_ = ((unsigned)(cb100 + (j) * 100)) & 1023u;      \
            if (pm_ >= 924u || pm_ < 6u) {                                     \
                s_hist[(lane_act && pA_ < 6u) ? (pA_ + 1024u) : dumpA] = accA; \
                s_hist[(lane_act && pB_ < 6u) ? (pB_ + 1024u) : dumpA] = accB; \
            }                                                                  \
        }                                                                      \
        if (DO_NEXT) {                                                         \
            const unsigned b2A =                                               \
                (unsigned)__float_as_int(CF[((j) + 1) & 1][0][2].x);           \
            const unsigned b2B =                                               \
                (unsigned)__float_as_int(CF[((j) + 1) & 1][1][2].x);           \
            const float2* wA = (const float2*)(s_hist + b2A);                  \
            const float2* wB = (const float2*)(s_hist + b2B);                  \
            const float2 a01 = wA[0], a23 = wA[1], a45 = wA[2], a67 = wA[3];   \
            const float2 b01 = wB[0], b23 = wB[1], b45 = wB[2], b67 = wB[3];   \
            hw[((j) & 1) ^ 1][0][0] = a01.x; hw[((j) & 1) ^ 1][0][1] = a01.y;  \
            hw[((j) & 1) ^ 1][0][2] = a23.x; hw[((j) & 1) ^ 1][0][3] = a23.y;  \
            hw[((j) & 1) ^ 1][0][4] = a45.x; hw[((j) & 1) ^ 1][0][5] = a45.y;  \
            hw[((j) & 1) ^ 1][0][6] = a67.x; hw[((j) & 1) ^ 1][0][7] = a67.y;  \
            hw[((j) & 1) ^ 1][1][0] = b01.x; hw[((j) & 1) ^ 1][1][1] = b01.y;  \
            hw[((j) & 1) ^ 1][1][2] = b23.x; hw[((j) & 1) ^ 1][1][3] = b23.y;  \
            hw[((j) & 1) ^ 1][1][4] = b45.x; hw[((j) & 1) ^ 1][1][5] = b45.y;  \
            hw[((j) & 1) ^ 1][1][6] = b67.x; hw[((j) & 1) ^ 1][1][7] = b67.y;  \
        }                                                                      \
    }

    // dump 800 samples of group g from the ring (coalesced, off-chain)
    #define DUMP800(g)                                                         \
    {                                                                          \
        const int t0 = (g) * 800;                                              \
        _Pragma("unroll")                                                      \
        for (int i = 0; i < 12; ++i) {                                         \
            int t = t0 + i * 64 + lane;                                        \
            out[t] = s_hist[((unsigned)t) & 1023u];                            \
        }                                                                      \
        {                                                                      \
            int t = t0 + 768 + lane;                                           \
            if (lane < 32) out[t] = s_hist[((unsigned)t) & 1023u];             \
        }                                                                      \
    }

    // groups 0..2 (bodies 0..23): excitation mix active (t < 2400 >= 2048)
    #pragma unroll 1
    for (int g = 0; g < 3; ++g) {
        float* cfc = s_cf[g & 1];
        float* cfn = s_cf[(g & 1) ^ 1];
        const int cb100 = g * 800;
        KS4_BODY(0, true, true)
        STAGE_GRP(g + 1)
        KS4_BODY(1, true, true)
        KS4_BODY(2, true, true)
        KS4_BODY(3, true, true)
        KS4_BODY(4, true, true)
        KS4_BODY(5, true, true)
        KS4_BODY(6, true, true)
        asm volatile("s_waitcnt vmcnt(0)" ::: "memory");
        KS4_BODY(7, true, true)
        DUMP800(g)
    }
    // groups 3..54: steady state
    #pragma unroll 1
    for (int g = 3; g < 55; ++g) {
        float* cfc = s_cf[g & 1];
        float* cfn = s_cf[(g & 1) ^ 1];
        const int cb100 = g * 800;
        KS4_BODY(0, false, true)
        STAGE_GRP(g + 1)
        KS4_BODY(1, false, true)
        KS4_BODY(2, false, true)
        KS4_BODY(3, false, true)
        KS4_BODY(4, false, true)
        KS4_BODY(5, false, true)
        KS4_BODY(6, false, true)
        asm volatile("s_waitcnt vmcnt(0)" ::: "memory");
        KS4_BODY(7, false, true)
        DUMP800(g)
    }
    // tail body 440 (slot 0, parity 0; coefs+window loaded by body 439)
    {
        float* cfc = s_cf[1];
        float* cfn = s_cf[0];
        const int cb100 = 44000;
        (void)cfc; (void)cfn;
        KS4_BODY(0, false, false)
    }
    // final dump: t in [44000, 44100)
    {
        int t = 44000 + lane;
        out[t] = s_hist[((unsigned)t) & 1023u];
        int t2 = t + 64;
        if (lane < 36) out[t2] = s_hist[((unsigned)t2) & 1023u];
    }
    #undef KS4_BODY
    #undef DUMP800
    #undef STAGE_GRP
}

// ------------------------------------------------- fallback (round-1 kernel)
#define CHUNK_FB  101
#define NCH_FB    ((T_SAMPLES + CHUNK_FB - 1) / CHUNK_FB)
#define HIST_FB   1024

__global__ __launch_bounds__(128) void diffks_fallback(
    const float* __restrict__ delay_frames,
    const float* __restrict__ excitation,
    const float* __restrict__ raw_coeff,
    const float* __restrict__ raw_gain,
    const float* __restrict__ exc_coeff,
    float* __restrict__ out)
{
    __shared__ float s_a[EXC_ORD][BURST];
    __shared__ float s_x[BURST];
    __shared__ float s_hist[HIST_FB];
    __shared__ __align__(16) float s_coef[NFRAMES][8];
    __shared__ float s_delay[NFRAMES];

    const int tid = threadIdx.x;
    const float gain = 0.1f / (1.0f + expf(-raw_gain[0])) + 0.9f;

    for (int i = tid; i < NFRAMES; i += 128) s_delay[i] = delay_frames[i];
    for (int f = tid; f < NFRAMES; f += 128) {
        float sb[NCOEF]; float s = 0.0f;
        #pragma unroll
        for (int j = 0; j < NCOEF; ++j) {
            sb[j] = 1.0f / (1.0f + expf(-raw_coeff[f * NCOEF + j]));
            s += sb[j];
        }
        float inv = gain / s;
        #pragma unroll
        for (int j = 0; j < NCOEF; ++j) s_coef[f][j] = sb[j] * inv;
        s_coef[f][6] = 0.0f; s_coef[f][7] = 0.0f;
    }
    const float stepE = 99.0f / 2047.0f;
    for (int t = tid; t < BURST; t += 128) {
        float pos = (float)t * stepE;
        int i0 = (int)pos; if (i0 > NFRAMES - 2) i0 = NFRAMES - 2;
        float w = pos - (float)i0;
        const float* c0 = exc_coeff + i0 * EXC_ORD;
        #pragma unroll
        for (int k = 0; k < EXC_ORD; ++k) {
            float a0 = c0[k], a1 = c0[k + EXC_ORD];
            s_a[k][t] = a0 + (a1 - a0) * w;
        }
        s_x[t] = excitation[t];
    }
    for (int i = tid; i < HIST_FB; i += 128) s_hist[i] = 0.0f;
    __syncthreads();

    if (tid == 0) {
        float y1 = 0.f, y2 = 0.f, y3 = 0.f, y4 = 0.f, y5 = 0.f;
        #pragma unroll 4
        for (int t = 0; t < BURST; ++t) {
            float p = s_x[t];
            p = fmaf(-s_a[1][t], y2, p);
            p = fmaf(-s_a[2][t], y3, p);
            p = fmaf(-s_a[3][t], y4, p);
            p = fmaf(-s_a[4][t], y5, p);
            float y = fmaf(-s_a[0][t], y1, p);
            s_x[t] = y;
            y5 = y4; y4 = y3; y3 = y2; y2 = y1; y1 = y;
        }
    }
    __syncthreads();

    const float stepT = 99.0f / (float)(T_SAMPLES - 1);
    for (int c = 0; c < NCH_FB; ++c) {
        int t = c * CHUNK_FB + tid;
        if (tid < CHUNK_FB && t < T_SAMPLES) {
            float pos = (float)t * stepT;
            int i0 = (int)pos; if (i0 > NFRAMES - 2) i0 = NFRAMES - 2;
            float w = pos - (float)i0;
            float d0 = s_delay[i0], d1 = s_delay[i0 + 1];
            float delay = d0 + (d1 - d0) * w;
            int z = (int)delay;
            float alfa = delay - (float)z;
            const float4* f0 = reinterpret_cast<const float4*>(s_coef[i0]);
            const float4* f1 = reinterpret_cast<const float4*>(s_coef[i0 + 1]);
            float4 c0a = f0[0], c0b = f0[1];
            float4 c1a = f1[0], c1b = f1[1];
            float b[NCOEF];
            b[0] = c0a.x + (c1a.x - c0a.x) * w;
            b[1] = c0a.y + (c1a.y - c0a.y) * w;
            b[2] = c0a.z + (c1a.z - c0a.z) * w;
            b[3] = c0a.w + (c1a.w - c0a.w) * w;
            b[4] = c0b.x + (c1b.x - c0b.x) * w;
            b[5] = c0b.y + (c1b.y - c0b.y) * w;
            float oma = 1.0f - alfa;
            float v[NACT];
            v[0] = -oma * b[0];
            #pragma unroll
            for (int j = 1; j <= 5; ++j) v[j] = -(alfa * b[j - 1] + oma * b[j]);
            v[6] = -alfa * b[5];
            float x = (t < BURST) ? s_x[t] : 0.0f;
            int base = t - z - 1;
            float sum = 0.0f;
            #pragma unroll
            for (int j = 0; j < NACT; ++j) {
                int idx = base - j;
                float yv = s_hist[idx & (HIST_FB - 1)];
                if (idx < 0) yv = 0.0f;
                sum = fmaf(v[j], yv, sum);
            }
            float y = x - sum;
            s_hist[t & (HIST_FB - 1)] = y;
            out[t] = y;
        }
        __syncthreads();
    }
}

// ---------------------------------------------------------------- launch
extern "C" void kernel_launch(void* const* d_in, const int* in_sizes, int n_in,
                              void* d_out, int out_size, void* d_ws, size_t ws_size,
                              hipStream_t stream) {
    const float* delay_frames = (const float*)d_in[0];
    const float* excitation   = (const float*)d_in[1];
    const float* raw_coeff    = (const float*)d_in[2];
    const float* raw_gain     = (const float*)d_in[3];
    const float* exc_coeff    = (const float*)d_in[4];
    float* out = (float*)d_out;

    if (ws_size >= WS_TOTAL_BYTES) {
        float* ws = (float*)d_ws;
        int gridA = (T_SAMPLES + BURST + 255) / 256;
        diffks_precompute<<<gridA, 256, 0, stream>>>(delay_frames, raw_coeff,
                                                     raw_gain, exc_coeff, ws);
        diffks_serial<<<1, 64, 0, stream>>>(excitation, ws, out);
    } else {
        diffks_fallback<<<1, 128, 0, stream>>>(delay_frames, excitation,
                                               raw_coeff, raw_gain, exc_coeff, out);
    }
}

// Round 5
// 180.580 us; speedup vs baseline: 1.0658x; 1.0658x over previous
//
#include <hip/hip_runtime.h>
#include <math.h>

// DiffKS round 8.
// Post-mortem fit across r3-r7: cost is ~8 cy per issued wave-instruction,
// ~constant per SAMPLE (6.5-7 cy) regardless of DS/VMEM structure — a lone
// wave pays full dependency latency on every instruction with no co-resident
// wave to fill gaps. Fix: 4 waves (256 threads), round-robin body ownership.
//   * body cc owned by wave cc&3; one raw s_barrier per body (lgkmcnt(0) +
//     s_barrier, no vmcnt drain);
//   * owner's slot = window ds_reads + 16 FMA + ring writes + out stores
//     (the true serial chain, ~250-300 cy);
//   * all prep (coef LDS reads, addresses, excitation) done by OTHER waves
//     in their idle slots: body n prepped at slot n-3 into a static 2-deep
//     per-wave register set (Ra/Rb);
//   * staging of group g+1: wave 1 issues 38x global_load_lds at slot 0,
//     s_waitcnt vmcnt(0) before the slot-4 barrier (publish).
// Math identical to r7 (aligned 8-slot windows, float2 reads, same FMA order).

#define T_SAMPLES 44100
#define NFRAMES   100
#define NCOEF     6
#define NACT      7
#define BURST     2048
#define EXC_ORD   5

#define C2        100           // samples per body
#define HISTSZ    1096          // 1024 ring + 6 mirror + pad + 64 dump slots
#define GRPF      9600          // 800 samples * 12 floats per group
#define CFBUF     9856          // 9728 staged (38x1KB) + 128 pad for reads

#define WS_COEF_FLOATS (T_SAMPLES * 12)
#define WS_EXC_OFF     WS_COEF_FLOATS
#define WS_EXC_FLOATS  (EXC_ORD * BURST)
#define WS_TOTAL_BYTES ((size_t)(WS_COEF_FLOATS + WS_EXC_FLOATS) * 4)

// ---------------------------------------------------------------- kernel A
__global__ __launch_bounds__(256) void diffks_precompute(
    const float* __restrict__ delay_frames,
    const float* __restrict__ raw_coeff,
    const float* __restrict__ raw_gain,
    const float* __restrict__ exc_coeff,
    float* __restrict__ ws)
{
    int g = blockIdx.x * 256 + threadIdx.x;
    const float gain = 0.1f / (1.0f + expf(-raw_gain[0])) + 0.9f;

    if (g < T_SAMPLES) {
        const float stepT = 99.0f / (float)(T_SAMPLES - 1);
        float pos = (float)g * stepT;
        int i0 = (int)pos; if (i0 > NFRAMES - 2) i0 = NFRAMES - 2;
        float w = pos - (float)i0;

        float d0 = delay_frames[i0], d1 = delay_frames[i0 + 1];
        float delay = d0 + (d1 - d0) * w;
        int z = (int)delay;                  // delay >= 100 > 0
        float alfa = delay - (float)z;

        float b[NCOEF];
        {
            float c0v[NCOEF], c1v[NCOEF];
            float s0 = 0.f, s1 = 0.f;
            #pragma unroll
            for (int j = 0; j < NCOEF; ++j) {
                c0v[j] = 1.0f / (1.0f + expf(-raw_coeff[i0 * NCOEF + j]));
                c1v[j] = 1.0f / (1.0f + expf(-raw_coeff[(i0 + 1) * NCOEF + j]));
                s0 += c0v[j]; s1 += c1v[j];
            }
            float g0 = gain / s0, g1 = gain / s1;
            #pragma unroll
            for (int j = 0; j < NCOEF; ++j) {
                float x0 = c0v[j] * g0, x1 = c1v[j] * g1;
                b[j] = x0 + (x1 - x0) * w;
            }
        }
        // v_j exactly as previous rounds (bit-identical), then negate (exact)
        float oma = 1.0f - alfa;
        float v0 = -oma * b[0];
        float v1 = -(alfa * b[0] + oma * b[1]);
        float v2 = -(alfa * b[1] + oma * b[2]);
        float v3 = -(alfa * b[2] + oma * b[3]);
        float v4 = -(alfa * b[3] + oma * b[4]);
        float v5 = -(alfa * b[4] + oma * b[5]);
        float v6 = -alfa * b[5];
        float pv0 = -v0, pv1 = -v1, pv2 = -v2, pv3 = -v3;
        float pv4 = -v4, pv5 = -v5, pv6 = -v6;

        int base = g - z - 1;
        int q = base - 6;                    // window = y[q .. q+6]
        int off = q & 1;
        unsigned b2 = ((unsigned)q) & 1022u; // (q & ~1) & 1023, 8B-aligned

        // shifted taps: m[off+6-j] = pv_j  (FMA iterates i = 7..0)
        float m0, m1, m2, m3, m4, m5, m6, m7;
        if (off) { m0 = 0.f; m1 = pv6; m2 = pv5; m3 = pv4;
                   m4 = pv3; m5 = pv2; m6 = pv1; m7 = pv0; }
        else     { m0 = pv6; m1 = pv5; m2 = pv4; m3 = pv3;
                   m4 = pv2; m5 = pv1; m6 = pv0; m7 = 0.f; }

        float4* o = (float4*)(ws + (size_t)g * 12);
        o[0] = make_float4(m0, m1, m2, m3);
        o[1] = make_float4(m4, m5, m6, m7);
        o[2] = make_float4(__int_as_float((int)b2), 0.f, 0.f, 0.f);
    } else if (g < T_SAMPLES + BURST) {
        int te = g - T_SAMPLES;
        const float stepE = 99.0f / (float)(BURST - 1);
        float pos = (float)te * stepE;
        int i0 = (int)pos; if (i0 > NFRAMES - 2) i0 = NFRAMES - 2;
        float w = pos - (float)i0;
        float* o = ws + WS_EXC_OFF + te * EXC_ORD;     // interleaved [t*5+k]
        #pragma unroll
        for (int k = 0; k < EXC_ORD; ++k) {
            float a0 = exc_coeff[i0 * EXC_ORD + k];
            float a1 = exc_coeff[(i0 + 1) * EXC_ORD + k];
            o[k] = a0 + (a1 - a0) * w;
        }
    }
}

// async global->LDS copy, 16B per lane; LDS base must be wave-uniform
__device__ __forceinline__ void gload_lds16(const float* g, float* l) {
    __builtin_amdgcn_global_load_lds(
        (const __attribute__((address_space(1))) unsigned int*)(g),
        (__attribute__((address_space(3))) unsigned int*)(l),
        16, 0, 0);
}

// ---------------------------------------------------------------- kernel B
__global__ __launch_bounds__(256, 1) void diffks_serial(
    const float* __restrict__ excitation,
    const float* __restrict__ ws,
    float* __restrict__ out)
{
    __shared__ float s_cf[2][CFBUF];     // coefficient double buffer (t-order)
    __shared__ float s_x[64][33];        // burst (padded rows)
    __shared__ float s_a[64][161];       // exc coefs [seg][(i%32)*5+k]
    __shared__ float s_hist[HISTSZ];     // 1024 ring + 6 mirror + 64 dump
    __shared__ float s_tail[64][32];
    __shared__ float s_bound[64][6];

    const int tid  = threadIdx.x;
    const int lane = tid & 63;
    const int wv   = tid >> 6;

    // ---- stage (all 256 threads) ----
    for (int t = tid; t < BURST; t += 256)
        s_x[t >> 5][t & 31] = excitation[t];
    for (int i = 0; i < 8; ++i) {        // exc coefs, 5 contiguous scalars
        int t = tid + i * 256;
        const float* g = ws + WS_EXC_OFF + t * EXC_ORD;
        float* dst = &s_a[t >> 5][(t & 31) * 5];
        dst[0] = g[0]; dst[1] = g[1]; dst[2] = g[2];
        dst[3] = g[3]; dst[4] = g[4];
    }
    for (int i = tid; i < HISTSZ; i += 256) s_hist[i] = 0.0f;
    __syncthreads();

    // ---- phase 1: excitation LPC via 64-segment state-space scan (wave 0) --
    if (tid < 64) {
        float st[6][5];
        #pragma unroll
        for (int r = 0; r < 6; ++r)
            #pragma unroll
            for (int k = 0; k < 5; ++k) st[r][k] = 0.0f;
        #pragma unroll
        for (int r = 1; r <= 5; ++r) st[r][r - 1] = 1.0f;

        const float* ar = &s_a[lane][0];
        const float* xr = &s_x[lane][0];
        #pragma unroll 8
        for (int i = 0; i < 32; ++i) {
            float a0 = ar[i * 5 + 0], a1 = ar[i * 5 + 1], a2 = ar[i * 5 + 2];
            float a3 = ar[i * 5 + 3], a4 = ar[i * 5 + 4];
            float xv = xr[i];
            #pragma unroll
            for (int r = 0; r < 6; ++r) {
                float acc = (r == 0) ? xv : 0.0f;
                acc = fmaf(-a0, st[r][0], acc);
                acc = fmaf(-a1, st[r][1], acc);
                acc = fmaf(-a2, st[r][2], acc);
                acc = fmaf(-a3, st[r][3], acc);
                acc = fmaf(-a4, st[r][4], acc);
                st[r][4] = st[r][3]; st[r][3] = st[r][2];
                st[r][2] = st[r][1]; st[r][1] = st[r][0];
                st[r][0] = acc;
            }
        }
        #pragma unroll
        for (int r = 0; r < 6; ++r)
            #pragma unroll
            for (int k = 0; k < 5; ++k)
                s_tail[lane][r * 5 + k] = st[r][k];
    }
    __syncthreads();

    if (tid == 0) {   // chain 5-dim boundary states through 64 segments
        float Y[5] = {0.f, 0.f, 0.f, 0.f, 0.f};
        for (int l = 0; l < 64; ++l) {
            #pragma unroll
            for (int c = 0; c < 5; ++c) s_bound[l][c] = Y[c];
            float tl[30];
            #pragma unroll
            for (int j = 0; j < 30; ++j) tl[j] = s_tail[l][j];
            float ny[5];
            #pragma unroll
            for (int k = 0; k < 5; ++k) {
                float acc = tl[k];
                #pragma unroll
                for (int c = 1; c <= 5; ++c)
                    acc = fmaf(tl[c * 5 + k], Y[c - 1], acc);
                ny[k] = acc;
            }
            #pragma unroll
            for (int k = 0; k < 5; ++k) Y[k] = ny[k];
        }
    }
    __syncthreads();

    if (tid < 64) {   // re-run each segment with correct boundary state
        float b0 = s_bound[lane][0], b1 = s_bound[lane][1], b2 = s_bound[lane][2];
        float b3 = s_bound[lane][3], b4 = s_bound[lane][4];
        const float* ar = &s_a[lane][0];
        float* xr = &s_x[lane][0];
        #pragma unroll 8
        for (int i = 0; i < 32; ++i) {
            float a0 = ar[i * 5 + 0], a1 = ar[i * 5 + 1], a2 = ar[i * 5 + 2];
            float a3 = ar[i * 5 + 3], a4 = ar[i * 5 + 4];
            float acc = xr[i];
            acc = fmaf(-a0, b0, acc);
            acc = fmaf(-a1, b1, acc);
            acc = fmaf(-a2, b2, acc);
            acc = fmaf(-a3, b3, acc);
            acc = fmaf(-a4, b4, acc);
            b4 = b3; b3 = b2; b2 = b1; b1 = b0; b0 = acc;
            xr[i] = acc;
        }
    }
    __syncthreads();

    // ---- phase 2: 4-wave round-robin resonator, C=100, 2 samples/lane ----
    const bool lane_act = (lane < 50);
    const unsigned dumpA = 1032u + (unsigned)lane;   // per-lane dump slot

    #define BBAR() asm volatile("s_waitcnt lgkmcnt(0)\n\ts_barrier" ::: "memory")

    #define STAGE_GRP(gg)                                                      \
    {                                                                          \
        float* dstb = &s_cf[(gg) & 1][0];                                      \
        const float* srcb = ws + (size_t)(gg) * GRPF + lane * 4;               \
        const int nis = ((gg) >= 55) ? 5 : 38;                                 \
        for (int i = 0; i < nis; ++i)                                          \
            gload_lds16(srcb + i * 256, dstb + i * 256);                       \
    }

    // per-wave prep register sets (a: slot wv, b: slot wv+4)
    float4 am0_a, am1_a, bm0_a, bm1_a;  unsigned b2A_a, b2B_a;  float xA_a, xB_a;
    float4 am0_b, am1_b, bm0_b, bm1_b;  unsigned b2A_b, b2B_b;  float xA_b, xB_b;

    // prep body with start t = BT0, sample index SLOT8*100+lane in BUF
    #define PREP(SET, BT0, SLOT8, BUF, WITHX_)                                 \
    {                                                                          \
        const int ln_ = (SLOT8) * 100 + lane;                                  \
        const float4* qA_ = (const float4*)((BUF) + ln_ * 12);                 \
        const float4* qB_ = (const float4*)((BUF) + (ln_ + 50) * 12);          \
        am0_##SET = qA_[0]; am1_##SET = qA_[1];                                \
        { float4 c2a_ = qA_[2];                                                \
          b2A_##SET = (unsigned)__float_as_int(c2a_.x); }                      \
        bm0_##SET = qB_[0]; bm1_##SET = qB_[1];                                \
        { float4 c2b_ = qB_[2];                                                \
          b2B_##SET = (unsigned)__float_as_int(c2b_.x); }                      \
        if (WITHX_) {                                                          \
            const int tAx_ = (BT0) + lane;                                     \
            const int tBx_ = tAx_ + 50;                                        \
            xA_##SET = (lane_act && tAx_ < BURST)                              \
                           ? s_x[(tAx_ >> 5) & 63][tAx_ & 31] : 0.0f;          \
            xB_##SET = (lane_act && tBx_ < BURST)                              \
                           ? s_x[(tBx_ >> 5) & 63][tBx_ & 31] : 0.0f;          \
        } else { xA_##SET = 0.0f; xB_##SET = 0.0f; }                           \
    }

    // owner compute: window reads -> 16 FMA (r7 order) -> ring writes ->
    // rare mirror branch -> direct out stores
    #define COMPUTE(SET, BT0)                                                  \
    {                                                                          \
        const int tA_ = (BT0) + lane;                                          \
        const int tB_ = tA_ + 50;                                              \
        const float2* wA_ = (const float2*)(s_hist + b2A_##SET);               \
        const float2* wB_ = (const float2*)(s_hist + b2B_##SET);               \
        const float2 a01 = wA_[0], a23 = wA_[1], a45 = wA_[2], a67 = wA_[3];   \
        const float2 b01 = wB_[0], b23 = wB_[1], b45 = wB_[2], b67 = wB_[3];   \
        const float4 am0 = am0_##SET, am1 = am1_##SET;                         \
        const float4 bm0 = bm0_##SET, bm1 = bm1_##SET;                         \
        float accA = xA_##SET, accB = xB_##SET;                                \
        accA = fmaf(am1.w, a67.y, accA);  accB = fmaf(bm1.w, b67.y, accB);     \
        accA = fmaf(am1.z, a67.x, accA);  accB = fmaf(bm1.z, b67.x, accB);     \
        accA = fmaf(am1.y, a45.y, accA);  accB = fmaf(bm1.y, b45.y, accB);     \
        accA = fmaf(am1.x, a45.x, accA);  accB = fmaf(bm1.x, b45.x, accB);     \
        accA = fmaf(am0.w, a23.y, accA);  accB = fmaf(bm0.w, b23.y, accB);     \
        accA = fmaf(am0.z, a23.x, accA);  accB = fmaf(bm0.z, b23.x, accB);     \
        accA = fmaf(am0.y, a01.y, accA);  accB = fmaf(bm0.y, b01.y, accB);     \
        accA = fmaf(am0.x, a01.x, accA);  accB = fmaf(bm0.x, b01.x, accB);     \
        const unsigned pA_ = ((unsigned)tA_) & 1023u;                          \
        const unsigned pB_ = ((unsigned)tB_) & 1023u;                          \
        s_hist[lane_act ? pA_ : dumpA] = accA;                                 \
        s_hist[lane_act ? pB_ : dumpA] = accB;                                 \
        {                                                                      \
            const unsigned pm_ = ((unsigned)(BT0)) & 1023u;                    \
            if (pm_ >= 924u || pm_ < 6u) {                                     \
                s_hist[(lane_act && pA_ < 6u) ? (pA_ + 1024u) : dumpA] = accA; \
                s_hist[(lane_act && pB_ < 6u) ? (pB_ + 1024u) : dumpA] = accB; \
            }                                                                  \
        }                                                                      \
        if (lane_act) { out[tA_] = accA; out[tB_] = accB; }                    \
    }

    // slot j of group g: owner computes; wave (j+3)&3 preps body j+3;
    // wave 1 stages next group at slot 0 and publishes before slot-4 barrier.
    #define SLOT(j, WITHXP_)                                                   \
    {                                                                          \
        if (wv == ((j) & 3)) {                                                 \
            if ((((j) >> 2) & 1)) { COMPUTE(b, cb100 + (j) * 100) }            \
            else                  { COMPUTE(a, cb100 + (j) * 100) }            \
        }                                                                      \
        if (wv == (((j) + 3) & 3)) {                                           \
            if (((((j) + 3) >> 2) & 1)) {      /* j=1..4 -> set b, cur buf */  \
                PREP(b, cb100 + ((j) + 3) * 100, (j) + 3, curb, WITHXP_)       \
            } else if ((j) + 3 < 4) {          /* j=0   -> set a, cur buf */   \
                PREP(a, cb100 + 300, 3, curb, WITHXP_)                         \
            } else {                           /* j=5..7 -> set a, next buf */ \
                PREP(a, cb100 + ((j) + 3) * 100, ((j) + 3) & 7, nxtb, WITHXP_) \
            }                                                                  \
        }                                                                      \
        if ((j) == 0 && wv == 1) { STAGE_GRP(g + 1) }                          \
        if ((j) == 4 && wv == 1) {                                             \
            asm volatile("s_waitcnt vmcnt(0)" ::: "memory");                   \
        }                                                                      \
        BBAR();                                                                \
    }

    // prologue: stage group 0 (wave 1), publish, prep bodies 0,1,2
    if (wv == 1) {
        STAGE_GRP(0)
        asm volatile("s_waitcnt vmcnt(0)" ::: "memory");
    }
    __syncthreads();
    {
        float* curb = &s_cf[0][0];
        if (wv == 0) { PREP(a, 0,   0, curb, true) }
        if (wv == 1) { PREP(a, 100, 1, curb, true) }
        if (wv == 2) { PREP(a, 200, 2, curb, true) }
    }
    __syncthreads();

    // groups 0..2: excitation-active preps (bodies <= 26; t<BURST check inside)
    #pragma unroll 1
    for (int g = 0; g < 3; ++g) {
        float* curb = &s_cf[g & 1][0];
        float* nxtb = &s_cf[(g + 1) & 1][0];
        const int cb100 = g * 800;
        SLOT(0, true) SLOT(1, true) SLOT(2, true) SLOT(3, true)
        SLOT(4, true) SLOT(5, true) SLOT(6, true) SLOT(7, true)
    }
    // groups 3..54: steady state
    #pragma unroll 1
    for (int g = 3; g < 55; ++g) {
        float* curb = &s_cf[g & 1][0];
        float* nxtb = &s_cf[(g + 1) & 1][0];
        const int cb100 = g * 800;
        SLOT(0, false) SLOT(1, false) SLOT(2, false) SLOT(3, false)
        SLOT(4, false) SLOT(5, false) SLOT(6, false) SLOT(7, false)
    }
    // tail body 440 (owner wave 0; prepped at slot 5 of g=54 from buf 1)
    if (wv == 0) { COMPUTE(a, 44000) }

    #undef SLOT
    #undef COMPUTE
    #undef PREP
    #undef STAGE_GRP
    #undef BBAR
}

// ------------------------------------------------- fallback (round-1 kernel)
#define CHUNK_FB  101
#define NCH_FB    ((T_SAMPLES + CHUNK_FB - 1) / CHUNK_FB)
#define HIST_FB   1024

__global__ __launch_bounds__(128) void diffks_fallback(
    const float* __restrict__ delay_frames,
    const float* __restrict__ excitation,
    const float* __restrict__ raw_coeff,
    const float* __restrict__ raw_gain,
    const float* __restrict__ exc_coeff,
    float* __restrict__ out)
{
    __shared__ float s_a[EXC_ORD][BURST];
    __shared__ float s_x[BURST];
    __shared__ float s_hist[HIST_FB];
    __shared__ __align__(16) float s_coef[NFRAMES][8];
    __shared__ float s_delay[NFRAMES];

    const int tid = threadIdx.x;
    const float gain = 0.1f / (1.0f + expf(-raw_gain[0])) + 0.9f;

    for (int i = tid; i < NFRAMES; i += 128) s_delay[i] = delay_frames[i];
    for (int f = tid; f < NFRAMES; f += 128) {
        float sb[NCOEF]; float s = 0.0f;
        #pragma unroll
        for (int j = 0; j < NCOEF; ++j) {
            sb[j] = 1.0f / (1.0f + expf(-raw_coeff[f * NCOEF + j]));
            s += sb[j];
        }
        float inv = gain / s;
        #pragma unroll
        for (int j = 0; j < NCOEF; ++j) s_coef[f][j] = sb[j] * inv;
        s_coef[f][6] = 0.0f; s_coef[f][7] = 0.0f;
    }
    const float stepE = 99.0f / 2047.0f;
    for (int t = tid; t < BURST; t += 128) {
        float pos = (float)t * stepE;
        int i0 = (int)pos; if (i0 > NFRAMES - 2) i0 = NFRAMES - 2;
        float w = pos - (float)i0;
        const float* c0 = exc_coeff + i0 * EXC_ORD;
        #pragma unroll
        for (int k = 0; k < EXC_ORD; ++k) {
            float a0 = c0[k], a1 = c0[k + EXC_ORD];
            s_a[k][t] = a0 + (a1 - a0) * w;
        }
        s_x[t] = excitation[t];
    }
    for (int i = tid; i < HIST_FB; i += 128) s_hist[i] = 0.0f;
    __syncthreads();

    if (tid == 0) {
        float y1 = 0.f, y2 = 0.f, y3 = 0.f, y4 = 0.f, y5 = 0.f;
        #pragma unroll 4
        for (int t = 0; t < BURST; ++t) {
            float p = s_x[t];
            p = fmaf(-s_a[1][t], y2, p);
            p = fmaf(-s_a[2][t], y3, p);
            p = fmaf(-s_a[3][t], y4, p);
            p = fmaf(-s_a[4][t], y5, p);
            float y = fmaf(-s_a[0][t], y1, p);
            s_x[t] = y;
            y5 = y4; y4 = y3; y3 = y2; y2 = y1; y1 = y;
        }
    }
    __syncthreads();

    const float stepT = 99.0f / (float)(T_SAMPLES - 1);
    for (int c = 0; c < NCH_FB; ++c) {
        int t = c * CHUNK_FB + tid;
        if (tid < CHUNK_FB && t < T_SAMPLES) {
            float pos = (float)t * stepT;
            int i0 = (int)pos; if (i0 > NFRAMES - 2) i0 = NFRAMES - 2;
            float w = pos - (float)i0;
            float d0 = s_delay[i0], d1 = s_delay[i0 + 1];
            float delay = d0 + (d1 - d0) * w;
            int z = (int)delay;
            float alfa = delay - (float)z;
            const float4* f0 = reinterpret_cast<const float4*>(s_coef[i0]);
            const float4* f1 = reinterpret_cast<const float4*>(s_coef[i0 + 1]);
            float4 c0a = f0[0], c0b = f0[1];
            float4 c1a = f1[0], c1b = f1[1];
            float b[NCOEF];
            b[0] = c0a.x + (c1a.x - c0a.x) * w;
            b[1] = c0a.y + (c1a.y - c0a.y) * w;
            b[2] = c0a.z + (c1a.z - c0a.z) * w;
            b[3] = c0a.w + (c1a.w - c0a.w) * w;
            b[4] = c0b.x + (c1b.x - c0b.x) * w;
            b[5] = c0b.y + (c1b.y - c0b.y) * w;
            float oma = 1.0f - alfa;
            float v[NACT];
            v[0] = -oma * b[0];
            #pragma unroll
            for (int j = 1; j <= 5; ++j) v[j] = -(alfa * b[j - 1] + oma * b[j]);
            v[6] = -alfa * b[5];
            float x = (t < BURST) ? s_x[t] : 0.0f;
            int base = t - z - 1;
            float sum = 0.0f;
            #pragma unroll
            for (int j = 0; j < NACT; ++j) {
                int idx = base - j;
                float yv = s_hist[idx & (HIST_FB - 1)];
                if (idx < 0) yv = 0.0f;
                sum = fmaf(v[j], yv, sum);
            }
            float y = x - sum;
            s_hist[t & (HIST_FB - 1)] = y;
            out[t] = y;
        }
        __syncthreads();
    }
}

// ---------------------------------------------------------------- launch
extern "C" void kernel_launch(void* const* d_in, const int* in_sizes, int n_in,
                              void* d_out, int out_size, void* d_ws, size_t ws_size,
                              hipStream_t stream) {
    const float* delay_frames = (const float*)d_in[0];
    const float* excitation   = (const float*)d_in[1];
    const float* raw_coeff    = (const float*)d_in[2];
    const float* raw_gain     = (const float*)d_in[3];
    const float* exc_coeff    = (const float*)d_in[4];
    float* out = (float*)d_out;

    if (ws_size >= WS_TOTAL_BYTES) {
        float* ws = (float*)d_ws;
        int gridA = (T_SAMPLES + BURST + 255) / 256;
        diffks_precompute<<<gridA, 256, 0, stream>>>(delay_frames, raw_coeff,
                                                     raw_gain, exc_coeff, ws);
        diffks_serial<<<1, 256, 0, stream>>>(excitation, ws, out);
    } else {
        diffks_fallback<<<1, 128, 0, stream>>>(delay_frames, excitation,
                                               raw_coeff, raw_gain, exc_coeff, out);
    }
}